// Round 7
// baseline (276.967 us; speedup 1.0000x reference)
//
#include <hip/hip_runtime.h>

// Problem: attention, q,k,v [B=4, N=2048, H=8, D=64] fp32 -> out same.
#define B 4
#define N 2048
#define H 8
#define D 64
#define HD 512              // row stride (elements) for fixed (b,h)
#define QT 128              // q rows per block (4 q-groups x 32, x 2 key-halves)
#define KT 64               // keys per tile
#define NT2 16              // tiles per key-half (split-K)
#define PLS 72              // prep-kernel LDS pad stride

typedef _Float16 half8 __attribute__((ext_vector_type(8)));
typedef float float4_ __attribute__((ext_vector_type(4)));
typedef float float16_ __attribute__((ext_vector_type(16)));

#define MFMA32(a, b, c) __builtin_amdgcn_mfma_f32_32x32x16_f16((a), (b), (c), 0, 0, 0)

// ---------------- fused prepass: K f32->f16 same layout; V -> Vt [b,h,d,n'] f16 ----------------
// Vt key axis is tau-permuted: position p holds original key tau(p), tau = swap bits 2<->3.
// tau makes the 32x32 MFMA S-tile D-rows line up with the PV A-operand k-slots per lane,
// so P never needs a cross-lane exchange (verified in R2).
__global__ void prep_kernel(const float* __restrict__ K, const float* __restrict__ V,
                            _Float16* __restrict__ Kf, _Float16* __restrict__ Vtr) {
    __shared__ _Float16 tile[64][PLS];
    const int t = threadIdx.x;
    if (blockIdx.x < 2048) {
        const size_t i = (size_t)blockIdx.x * 256 + t;
        const float4_* p = (const float4_*)(K + i * 8);
        float4_ a = p[0], b = p[1];
        half8 hh;
        #pragma unroll
        for (int j = 0; j < 4; ++j) { hh[j] = (_Float16)a[j]; hh[4 + j] = (_Float16)b[j]; }
        *(half8*)(Kf + i * 8) = hh;
    } else {
        const int bid = blockIdx.x - 2048;
        const int nt = bid & 31, h = (bid >> 5) & 7, b = bid >> 8;
        {
            const int i = t >> 2, c0 = (t & 3) * 16;
            const float* vp = V + (size_t)b * N * HD + (size_t)(nt * 64 + i) * HD + h * D + c0;
            #pragma unroll
            for (int j = 0; j < 4; ++j) {
                float4_ a = *(const float4_*)(vp + j * 4);
                #pragma unroll
                for (int c = 0; c < 4; ++c) tile[i][c0 + j * 4 + c] = (_Float16)a[c];
            }
        }
        __syncthreads();
        {
            const int d = t >> 2, n0 = (t & 3) * 16;
            // tau within the 16-run: positions n0+0..7 hold keys n0+{0,1,2,3,8,9,10,11};
            //                        positions n0+8..15 hold keys n0+{4,5,6,7,12,13,14,15}.
            half8 w0, w1;
            #pragma unroll
            for (int j = 0; j < 4; ++j) {
                w0[j]     = tile[n0 + j][d];
                w0[4 + j] = tile[n0 + 8 + j][d];
                w1[j]     = tile[n0 + 4 + j][d];
                w1[4 + j] = tile[n0 + 12 + j][d];
            }
            _Float16* op = Vtr + ((size_t)(b * H + h) * D + d) * N + nt * 64 + n0;
            *(half8*)op = w0;
            *(half8*)(op + 8) = w1;
        }
    }
}

// ------- async staging (chunk-swizzled, group-split); wg in [0,4) covers 16 rows each -------
__device__ __forceinline__ void stage_k(const _Float16* __restrict__ Kbh, int keybase,
                                        _Float16* kb, int wg, int lane) {
    const int rsub = lane >> 3, slot = lane & 7;
    #pragma unroll
    for (int i = 0; i < 2; ++i) {
        const int row = wg * 16 + i * 8 + rsub;
        const int c = slot ^ (row & 7);
        __builtin_amdgcn_global_load_lds(
            (const __attribute__((address_space(1))) void*)(Kbh + (size_t)(keybase + row) * HD + c * 8),
            (__attribute__((address_space(3))) void*)(kb + (wg * 16 + i * 8) * 64), 16, 0, 0);
    }
}
__device__ __forceinline__ void stage_v(const _Float16* __restrict__ Vbh, int keybase,
                                        _Float16* vb, int wg, int lane) {
    const int rsub = lane >> 3, slot = lane & 7;
    #pragma unroll
    for (int i = 0; i < 2; ++i) {
        const int row = wg * 16 + i * 8 + rsub;      // d row
        const int c = slot ^ (row & 7);
        __builtin_amdgcn_global_load_lds(
            (const __attribute__((address_space(1))) void*)(Vbh + (size_t)row * N + keybase + c * 8),
            (__attribute__((address_space(3))) void*)(vb + (wg * 16 + i * 8) * 64), 16, 0, 0);
    }
}

// ---- per-phase compute pieces (macros keep pfA/pfB indexing static — rule 20) ----
#define DO_S(KC, PFC)                                                              \
    {                                                                              \
        _Pragma("unroll")                                                          \
        for (int kb = 0; kb < 2; ++kb) {                                           \
            float16_ s = {};                                                       \
            __builtin_amdgcn_s_setprio(1);                                         \
            _Pragma("unroll")                                                      \
            for (int ks = 0; ks < 4; ++ks) {                                       \
                const int csw = ((2 * ks + hi) ^ (ln & 7)) * 8;                    \
                half8 a = *(const half8*)((KC) + (kb * 32 + ln) * 64 + csw);       \
                s = MFMA32(a, qf[ks], s);                                          \
            }                                                                      \
            __builtin_amdgcn_s_setprio(0);                                         \
            half8 f0, f1;                                                          \
            _Pragma("unroll")                                                      \
            for (int j = 0; j < 8; ++j) {                                          \
                float pa = __builtin_amdgcn_exp2f(s[j]);                           \
                float pb = __builtin_amdgcn_exp2f(s[8 + j]);                       \
                ls0 += pa; ls1 += pb;                                              \
                f0[j] = (_Float16)pa;                                              \
                f1[j] = (_Float16)pb;                                              \
            }                                                                      \
            PFC[2 * kb]     = f0;                                                  \
            PFC[2 * kb + 1] = f1;                                                  \
        }                                                                          \
    }

#define DO_PV(VC, PFP)                                                             \
    {                                                                              \
        __builtin_amdgcn_s_setprio(1);                                             \
        _Pragma("unroll")                                                          \
        for (int ks = 0; ks < 4; ++ks) {                                           \
            const int csw = ((2 * ks + hi) ^ (ln & 7)) * 8;                        \
            half8 b0 = *(const half8*)((VC) + ln * 64 + csw);                      \
            half8 b1 = *(const half8*)((VC) + (32 + ln) * 64 + csw);               \
            o0 = MFMA32(PFP[ks], b0, o0);                                          \
            o1 = MFMA32(PFP[ks], b1, o1);                                          \
        }                                                                          \
        __builtin_amdgcn_s_setprio(0);                                             \
    }

// Phase T: wait tile T, barrier, S(T)->PFC, PV(T-1) with PFP (V slot (T-1)%3 == (T+2)%3),
// barrier, stage tile T+2 (K dbuf slot T&1, V tbuf slot (T+2)%3).
#define PHASE(T, PFC, PFP, WITHPV)                                                 \
    {                                                                              \
        if ((T) < NT2 - 1) asm volatile("s_waitcnt vmcnt(4)" ::: "memory");        \
        else               asm volatile("s_waitcnt vmcnt(0)" ::: "memory");        \
        __builtin_amdgcn_s_barrier();                                              \
        __builtin_amdgcn_sched_barrier(0);                                         \
        const _Float16* kc_ = Kb + ((T) & 1) * 4096;                               \
        DO_S(kc_, PFC)                                                             \
        if (WITHPV) {                                                              \
            const _Float16* vp_ = Vb + (((T) + 2) % 3) * 4096;                     \
            DO_PV(vp_, PFP)                                                        \
        }                                                                          \
        if ((T) + 2 < NT2) {                                                       \
            __builtin_amdgcn_s_barrier();                                          \
            __builtin_amdgcn_sched_barrier(0);                                     \
            stage_k(Kbh, tbase + ((T) + 2) * KT, Kb + ((T) & 1) * 4096, qg, lane); \
            stage_v(Vbh, tbase + ((T) + 2) * KT, Vb + (((T) + 2) % 3) * 4096, qg, lane); \
        }                                                                          \
    }

// ---- main: split-K, 8 waves (4 qg x 2 kh), PV(t-1)||S(t) via pf-dbuf, K dbuf + V tbuf ----
__global__ __launch_bounds__(512, 4)
void fattn11_kernel(const float* __restrict__ Q, const _Float16* __restrict__ Kf,
                    const _Float16* __restrict__ Vt, float* __restrict__ Out)
{
    // 80 KB: per stream K dbuf 2x4096 + V tbuf 3x4096 (halves). Epilogue reuses as f32 scratch.
    static __shared__ __align__(16) _Float16 smem[40960];

    const int tid  = threadIdx.x;
    const int wave = tid >> 6;
    const int lane = tid & 63;
    const int ln   = lane & 31;
    const int hi   = lane >> 5;
    const int qg   = wave & 3;      // q-group: 32 q-rows
    const int kh   = wave >> 2;     // key-half: tiles [kh*16, kh*16+16)

    const int h = blockIdx.y;
    const int b = blockIdx.z;
    const int q_base = blockIdx.x * QT + qg * 32;

    const size_t bh_q = (size_t)b * N * HD + (size_t)h * D;
    const _Float16* Kbh = Kf + bh_q;
    const _Float16* Vbh = Vt + (size_t)(b * H + h) * D * N;

    _Float16* Kb = smem + kh * 8192;             // [2][4096]
    _Float16* Vb = smem + 16384 + kh * 12288;    // [3][4096]

    // Q rows in registers as S^T B-frags: qf[ks][j] = Q[q_base+ln][ks*16+hi*8+j]*SC
    const float SC = 0.125f * 1.4426950408889634f;
    half8 qf[4];
    {
        const float* qp = Q + bh_q + (size_t)(q_base + ln) * HD + hi * 8;
        #pragma unroll
        for (int ks = 0; ks < 4; ++ks) {
            float4_ a0 = *(const float4_*)(qp + ks * 16);
            float4_ a1 = *(const float4_*)(qp + ks * 16 + 4);
            half8 f;
            #pragma unroll
            for (int j = 0; j < 4; ++j) { f[j] = (_Float16)(a0[j] * SC); f[4 + j] = (_Float16)(a1[j] * SC); }
            qf[ks] = f;
        }
    }

    float16_ o0 = {}, o1 = {};
    float ls0 = 0.f, ls1 = 0.f;
    half8 pfA[4], pfB[4];

    const int tbase = kh * NT2 * KT;

    // prologue: stage tiles 0 and 1 (K slots 0,1; V slots 0,1); 8 vmem ops per wave
    stage_k(Kbh, tbase, Kb, qg, lane);              stage_v(Vbh, tbase, Vb, qg, lane);
    stage_k(Kbh, tbase + KT, Kb + 4096, qg, lane);  stage_v(Vbh, tbase + KT, Vb + 4096, qg, lane);

    // phase 0: S(0)->pfA only
    PHASE(0, pfA, pfB, false)
    // phases 1..14: PV(t-1) || S(t), alternating pf roles (even trip count -> static parity)
    for (int t = 1; t < NT2 - 1; t += 2) {
        PHASE(t,     pfB, pfA, true)
        PHASE(t + 1, pfA, pfB, true)
    }
    // phase 15: PV(14,pfA) || S(15)->pfB
    PHASE(NT2 - 1, pfB, pfA, true)
    // final: PV(15) with pfB; V slot 15%3 = 0 (resident since phase-15 wait)
    {
        const _Float16* vp_ = Vb + ((NT2 - 1) % 3) * 4096;
        DO_PV(vp_, pfB)
    }
    float lsum = ls0 + ls1;

    // ---- combine epilogue: sum the two key-half partials through LDS ----
    __syncthreads();                           // all waves done reading K/V LDS
    float* cb = (float*)smem;                  // [qg][dh][r][lane] = 8192 floats (32 KB)
    float* ls = cb + 4 * 2 * 16 * 64;          // [qg][lane] = 256 floats
    if (kh == 1) {
        #pragma unroll
        for (int r = 0; r < 16; ++r) {
            cb[((qg * 2 + 0) * 16 + r) * 64 + lane] = o0[r];
            cb[((qg * 2 + 1) * 16 + r) * 64 + lane] = o1[r];
        }
        ls[qg * 64 + lane] = lsum;
    }
    __syncthreads();
    if (kh == 0) {
        #pragma unroll
        for (int r = 0; r < 16; ++r) {
            o0[r] += cb[((qg * 2 + 0) * 16 + r) * 64 + lane];
            o1[r] += cb[((qg * 2 + 1) * 16 + r) * 64 + lane];
        }
        lsum += ls[qg * 64 + lane];
        // finalize: per-lane row sums (q = ln, split by hi); combine halves, store
        float v = lsum;
        v += __shfl_xor(v, 32, 64);
        const float inv = 1.0f / v;
        #pragma unroll
        for (int r = 0; r < 16; ++r) {
            const int rl = (r & 3) + 8 * (r >> 2) + 4 * hi;
            const float linv = __shfl(inv, rl, 64);
            const size_t ro = bh_q + (size_t)(q_base + rl) * HD;
            Out[ro + ln]      = o0[r] * linv;
            Out[ro + 32 + ln] = o1[r] * linv;
        }
    }
}

// ---------------- fallback (round-1 verified kernel) if ws too small ----------------
__global__ __launch_bounds__(256, 2)
void fattn_fb_kernel(const float* __restrict__ Q, const float* __restrict__ K,
                     const float* __restrict__ V, float* __restrict__ Out)
{
    __shared__ __align__(16) _Float16 Ks[KT][PLS];
    __shared__ __align__(16) _Float16 Vts[D][PLS];
    __shared__ __align__(16) _Float16 Pwf[4][16][PLS];
    const int tid = threadIdx.x, wave = tid >> 6, lane = tid & 63;
    const int m = lane & 15, quad = lane >> 4;
    const int q_base = blockIdx.x * 64;
    const size_t bh_off = ((size_t)blockIdx.z * N * H + (size_t)blockIdx.y) * D;
    const float SCALE = 0.125f;
    const int qrow = q_base + wave * 16 + m;
    const float* qp = Q + bh_off + (size_t)qrow * HD + quad * 8;
    half8 qf0, qf1;
    #pragma unroll
    for (int j = 0; j < 8; ++j) qf0[j] = (_Float16)(qp[j] * SCALE);
    #pragma unroll
    for (int j = 0; j < 8; ++j) qf1[j] = (_Float16)(qp[32 + j] * SCALE);
    float4_ o[4] = {};
    float mi[4], li[4];
    #pragma unroll
    for (int r = 0; r < 4; ++r) { mi[r] = -1e30f; li[r] = 0.0f; }
    for (int kt = 0; kt < N; kt += KT) {
        __syncthreads();
        {
            const int key = tid >> 2, c0 = (tid & 3) * 16;
            const float* kp = K + bh_off + (size_t)(kt + key) * HD + c0;
            half8 lo, hi;
            #pragma unroll
            for (int j = 0; j < 8; ++j) lo[j] = (_Float16)kp[j];
            #pragma unroll
            for (int j = 0; j < 8; ++j) hi[j] = (_Float16)kp[8 + j];
            *(half8*)&Ks[key][c0] = lo;
            *(half8*)&Ks[key][c0 + 8] = hi;
        }
        {
            const int c0 = (tid & 15) * 4, k0 = (tid >> 4) * 4;
            const float* vp = V + bh_off + (size_t)(kt + k0) * HD + c0;
            #pragma unroll
            for (int c = 0; c < 4; ++c)
                #pragma unroll
                for (int i = 0; i < 4; ++i)
                    Vts[c0 + c][k0 + i] = (_Float16)vp[i * HD + c];
        }
        __syncthreads();
        float4_ s[4];
        #pragma unroll
        for (int blk = 0; blk < 4; ++blk) {
            const int key = blk * 16 + m;
            half8 kf0 = *(const half8*)&Ks[key][quad * 8];
            half8 kf1 = *(const half8*)&Ks[key][32 + quad * 8];
            float4_ acc = {};
            acc = __builtin_amdgcn_mfma_f32_16x16x32_f16(qf0, kf0, acc, 0, 0, 0);
            acc = __builtin_amdgcn_mfma_f32_16x16x32_f16(qf1, kf1, acc, 0, 0, 0);
            s[blk] = acc;
        }
        float alpha[4];
        #pragma unroll
        for (int r = 0; r < 4; ++r) {
            float v0 = fmaxf(fmaxf(s[0][r], s[1][r]), fmaxf(s[2][r], s[3][r]));
            #pragma unroll
            for (int mask = 1; mask < 16; mask <<= 1) v0 = fmaxf(v0, __shfl_xor(v0, mask, 64));
            float mn = fmaxf(mi[r], v0);
            alpha[r] = __expf(mi[r] - mn);
            mi[r] = mn;
        }
        #pragma unroll
        for (int blk = 0; blk < 4; ++blk)
            #pragma unroll
            for (int r = 0; r < 4; ++r) s[blk][r] = __expf(s[blk][r] - mi[r]);
        #pragma unroll
        for (int r = 0; r < 4; ++r) {
            float tt = s[0][r] + s[1][r] + s[2][r] + s[3][r];
            #pragma unroll
            for (int mask = 1; mask < 16; mask <<= 1) tt += __shfl_xor(tt, mask, 64);
            li[r] = li[r] * alpha[r] + tt;
        }
        #pragma unroll
        for (int d = 0; d < 4; ++d)
            #pragma unroll
            for (int r = 0; r < 4; ++r) o[d][r] *= alpha[r];
        #pragma unroll
        for (int blk = 0; blk < 4; ++blk)
            #pragma unroll
            for (int r = 0; r < 4; ++r)
                Pwf[wave][quad * 4 + r][blk * 16 + m] = (_Float16)s[blk][r];
        #pragma unroll
        for (int ks = 0; ks < 2; ++ks) {
            half8 af = *(const half8*)&Pwf[wave][m][ks * 32 + quad * 8];
            #pragma unroll
            for (int d = 0; d < 4; ++d) {
                half8 bf = *(const half8*)&Vts[d * 16 + m][ks * 32 + quad * 8];
                o[d] = __builtin_amdgcn_mfma_f32_16x16x32_f16(af, bf, o[d], 0, 0, 0);
            }
        }
    }
    #pragma unroll
    for (int d = 0; d < 4; ++d)
        #pragma unroll
        for (int r = 0; r < 4; ++r) {
            const int row = q_base + wave * 16 + quad * 4 + r;
            Out[bh_off + (size_t)row * HD + d * 16 + m] = o[d][r] / li[r];
        }
}

extern "C" void kernel_launch(void* const* d_in, const int* in_sizes, int n_in,
                              void* d_out, int out_size, void* d_ws, size_t ws_size,
                              hipStream_t stream) {
    const float* q = (const float*)d_in[0];
    const float* k = (const float*)d_in[1];
    const float* v = (const float*)d_in[2];
    float* out = (float*)d_out;

    const size_t nelem = (size_t)B * N * H * D;           // 4194304
    const size_t need = 2 * nelem * sizeof(_Float16);     // Kf + Vt

    if (ws_size >= need) {
        _Float16* Kf = (_Float16*)d_ws;
        _Float16* Vtr = Kf + nelem;
        prep_kernel<<<dim3(2048 + 1024), 256, 0, stream>>>(k, v, Kf, Vtr);
        fattn11_kernel<<<dim3(N / QT, H, B), 512, 0, stream>>>(q, Kf, Vtr, out);
    } else {
        fattn_fb_kernel<<<dim3(N / 64, H, B), 256, 0, stream>>>(q, k, v, out);
    }
}

// Round 8
// 250.483 us; speedup vs baseline: 1.1057x; 1.1057x over previous
//
#include <hip/hip_runtime.h>

// Problem: attention, q,k,v [B=4, N=2048, H=8, D=64] fp32 -> out same.
#define B 4
#define N 2048
#define H 8
#define D 64
#define HD 512              // row stride (elements) for fixed (b,h)
#define QT 128              // q rows per block (4 q-groups x 32, x 2 key-halves)
#define KT 64               // keys per tile
#define NT2 16              // tiles per key-half (split-K)
#define PLS 72              // prep-kernel LDS pad stride

typedef _Float16 half8 __attribute__((ext_vector_type(8)));
typedef float float4_ __attribute__((ext_vector_type(4)));
typedef float float16_ __attribute__((ext_vector_type(16)));

#define MFMA32(a, b, c) __builtin_amdgcn_mfma_f32_32x32x16_f16((a), (b), (c), 0, 0, 0)

// ---------------- fused prepass: K f32->f16 same layout; V -> Vt [b,h,d,n'] f16 ----------------
// Vt key axis is tau-permuted: position p holds original key tau(p), tau = swap bits 2<->3.
// tau makes the 32x32 MFMA S-tile D-rows line up with the PV A-operand k-slots per lane,
// so P never needs a cross-lane exchange (verified in R2).
__global__ void prep_kernel(const float* __restrict__ K, const float* __restrict__ V,
                            _Float16* __restrict__ Kf, _Float16* __restrict__ Vtr) {
    __shared__ _Float16 tile[64][PLS];
    const int t = threadIdx.x;
    if (blockIdx.x < 2048) {
        const size_t i = (size_t)blockIdx.x * 256 + t;
        const float4_* p = (const float4_*)(K + i * 8);
        float4_ a = p[0], b = p[1];
        half8 hh;
        #pragma unroll
        for (int j = 0; j < 4; ++j) { hh[j] = (_Float16)a[j]; hh[4 + j] = (_Float16)b[j]; }
        *(half8*)(Kf + i * 8) = hh;
    } else {
        const int bid = blockIdx.x - 2048;
        const int nt = bid & 31, h = (bid >> 5) & 7, b = bid >> 8;
        {
            const int i = t >> 2, c0 = (t & 3) * 16;
            const float* vp = V + (size_t)b * N * HD + (size_t)(nt * 64 + i) * HD + h * D + c0;
            #pragma unroll
            for (int j = 0; j < 4; ++j) {
                float4_ a = *(const float4_*)(vp + j * 4);
                #pragma unroll
                for (int c = 0; c < 4; ++c) tile[i][c0 + j * 4 + c] = (_Float16)a[c];
            }
        }
        __syncthreads();
        {
            const int d = t >> 2, n0 = (t & 3) * 16;
            // tau within the 16-run: positions n0+0..7 hold keys n0+{0,1,2,3,8,9,10,11};
            //                        positions n0+8..15 hold keys n0+{4,5,6,7,12,13,14,15}.
            half8 w0, w1;
            #pragma unroll
            for (int j = 0; j < 4; ++j) {
                w0[j]     = tile[n0 + j][d];
                w0[4 + j] = tile[n0 + 8 + j][d];
                w1[j]     = tile[n0 + 4 + j][d];
                w1[4 + j] = tile[n0 + 12 + j][d];
            }
            _Float16* op = Vtr + ((size_t)(b * H + h) * D + d) * N + nt * 64 + n0;
            *(half8*)op = w0;
            *(half8*)(op + 8) = w1;
        }
    }
}

// ------- async staging (chunk-swizzled, group-split); wg in [0,4) covers 16 rows each -------
__device__ __forceinline__ void stage_k(const _Float16* __restrict__ Kbh, int keybase,
                                        _Float16* kb, int wg, int lane) {
    const int rsub = lane >> 3, slot = lane & 7;
    #pragma unroll
    for (int i = 0; i < 2; ++i) {
        const int row = wg * 16 + i * 8 + rsub;
        const int c = slot ^ (row & 7);
        __builtin_amdgcn_global_load_lds(
            (const __attribute__((address_space(1))) void*)(Kbh + (size_t)(keybase + row) * HD + c * 8),
            (__attribute__((address_space(3))) void*)(kb + (wg * 16 + i * 8) * 64), 16, 0, 0);
    }
}
__device__ __forceinline__ void stage_v(const _Float16* __restrict__ Vbh, int keybase,
                                        _Float16* vb, int wg, int lane) {
    const int rsub = lane >> 3, slot = lane & 7;
    #pragma unroll
    for (int i = 0; i < 2; ++i) {
        const int row = wg * 16 + i * 8 + rsub;      // d row
        const int c = slot ^ (row & 7);
        __builtin_amdgcn_global_load_lds(
            (const __attribute__((address_space(1))) void*)(Vbh + (size_t)row * N + keybase + c * 8),
            (__attribute__((address_space(3))) void*)(vb + (wg * 16 + i * 8) * 64), 16, 0, 0);
    }
}

// ---- per-phase compute pieces. ALL P fragments are NAMED scalars (rule 20: the R7
// ---- pfA[4]/pfB[4] arrays lived across iterations, failed SROA, went to scratch:
// ---- WRITE_SIZE 16->422 MB. Macros thread the names through; zero dynamic indexing. ----
#define DO_S_HALF(KC, KB, PA, PB)                                              \
    {                                                                          \
        float16_ s = {};                                                       \
        __builtin_amdgcn_s_setprio(1);                                         \
        _Pragma("unroll")                                                      \
        for (int ks = 0; ks < 4; ++ks) {                                       \
            const int csw = ((2 * ks + hi) ^ (ln & 7)) * 8;                    \
            half8 a = *(const half8*)((KC) + ((KB) * 32 + ln) * 64 + csw);     \
            s = MFMA32(a, qf[ks], s);                                          \
        }                                                                      \
        __builtin_amdgcn_s_setprio(0);                                         \
        half8 f0, f1;                                                          \
        _Pragma("unroll")                                                      \
        for (int j = 0; j < 8; ++j) {                                          \
            float pa_ = __builtin_amdgcn_exp2f(s[j]);                          \
            float pb_ = __builtin_amdgcn_exp2f(s[8 + j]);                      \
            ls0 += pa_; ls1 += pb_;                                            \
            f0[j] = (_Float16)pa_;                                             \
            f1[j] = (_Float16)pb_;                                             \
        }                                                                      \
        PA = f0; PB = f1;                                                      \
    }

#define PV_STEP(VC, KS, P)                                                     \
    {                                                                          \
        const int csw = ((2 * (KS) + hi) ^ (ln & 7)) * 8;                      \
        half8 b0 = *(const half8*)((VC) + ln * 64 + csw);                      \
        half8 b1 = *(const half8*)((VC) + (32 + ln) * 64 + csw);               \
        o0 = MFMA32(P, b0, o0);                                                \
        o1 = MFMA32(P, b1, o1);                                                \
    }

#define DO_PV(VC, P0, P1, P2, P3)                                              \
    __builtin_amdgcn_s_setprio(1);                                             \
    PV_STEP(VC, 0, P0) PV_STEP(VC, 1, P1)                                      \
    PV_STEP(VC, 2, P2) PV_STEP(VC, 3, P3)                                      \
    __builtin_amdgcn_s_setprio(0);

// Phase T: wait tile T (counted), barrier, S(T)->C0..C3, PV(T-1) from Pp0..Pp3
// (V slot (T-1)%3 == (T+2)%3), barrier, stage tile T+2 (K slot T&1, V slot (T+2)%3).
#define PHASE(T, C0, C1, C2, C3, Pp0, Pp1, Pp2, Pp3, WITHPV)                   \
    {                                                                          \
        if ((T) < NT2 - 1) asm volatile("s_waitcnt vmcnt(4)" ::: "memory");    \
        else               asm volatile("s_waitcnt vmcnt(0)" ::: "memory");    \
        __builtin_amdgcn_s_barrier();                                          \
        __builtin_amdgcn_sched_barrier(0);                                     \
        const _Float16* kc_ = Kb + ((T) & 1) * 4096;                           \
        DO_S_HALF(kc_, 0, C0, C1)                                              \
        DO_S_HALF(kc_, 1, C2, C3)                                              \
        if (WITHPV) {                                                          \
            const _Float16* vp_ = Vb + (((T) + 2) % 3) * 4096;                 \
            DO_PV(vp_, Pp0, Pp1, Pp2, Pp3)                                     \
        }                                                                      \
        if ((T) + 2 < NT2) {                                                   \
            __builtin_amdgcn_s_barrier();                                      \
            __builtin_amdgcn_sched_barrier(0);                                 \
            stage_k(Kbh, tbase + ((T) + 2) * KT, Kb + ((T) & 1) * 4096, qg, lane); \
            stage_v(Vbh, tbase + ((T) + 2) * KT, Vb + (((T) + 2) % 3) * 4096, qg, lane); \
        }                                                                      \
    }

// ---- main: split-K, 8 waves (4 qg x 2 kh), PV(t-1)||S(t) via named pf-dbuf, K dbuf + V tbuf ----
__global__ __launch_bounds__(512, 4)
void fattn12_kernel(const float* __restrict__ Q, const _Float16* __restrict__ Kf,
                    const _Float16* __restrict__ Vt, float* __restrict__ Out)
{
    // 80 KB: per stream K dbuf 2x4096 + V tbuf 3x4096 (halves). Epilogue reuses as f32 scratch.
    static __shared__ __align__(16) _Float16 smem[40960];

    const int tid  = threadIdx.x;
    const int wave = tid >> 6;
    const int lane = tid & 63;
    const int ln   = lane & 31;
    const int hi   = lane >> 5;
    const int qg   = wave & 3;      // q-group: 32 q-rows
    const int kh   = wave >> 2;     // key-half: tiles [kh*16, kh*16+16)

    const int h = blockIdx.y;
    const int b = blockIdx.z;
    const int q_base = blockIdx.x * QT + qg * 32;

    const size_t bh_q = (size_t)b * N * HD + (size_t)h * D;
    const _Float16* Kbh = Kf + bh_q;
    const _Float16* Vbh = Vt + (size_t)(b * H + h) * D * N;

    _Float16* Kb = smem + kh * 8192;             // [2][4096]
    _Float16* Vb = smem + 16384 + kh * 12288;    // [3][4096]

    // Q rows in registers as S^T B-frags: qf[ks][j] = Q[q_base+ln][ks*16+hi*8+j]*SC
    const float SC = 0.125f * 1.4426950408889634f;
    half8 qf[4];
    {
        const float* qp = Q + bh_q + (size_t)(q_base + ln) * HD + hi * 8;
        #pragma unroll
        for (int ks = 0; ks < 4; ++ks) {
            float4_ a0 = *(const float4_*)(qp + ks * 16);
            float4_ a1 = *(const float4_*)(qp + ks * 16 + 4);
            half8 f;
            #pragma unroll
            for (int j = 0; j < 4; ++j) { f[j] = (_Float16)(a0[j] * SC); f[4 + j] = (_Float16)(a1[j] * SC); }
            qf[ks] = f;
        }
    }

    float16_ o0 = {}, o1 = {};
    float ls0 = 0.f, ls1 = 0.f;
    half8 pa0, pa1, pa2, pa3;       // P fragments, phase parity A
    half8 pb0, pb1, pb2, pb3;       // P fragments, phase parity B

    const int tbase = kh * NT2 * KT;

    // prologue: stage tiles 0 and 1 (K slots 0,1; V slots 0,1); 8 vmem ops per wave
    stage_k(Kbh, tbase, Kb, qg, lane);              stage_v(Vbh, tbase, Vb, qg, lane);
    stage_k(Kbh, tbase + KT, Kb + 4096, qg, lane);  stage_v(Vbh, tbase + KT, Vb + 4096, qg, lane);

    // phase 0: S(0)->pa only
    PHASE(0, pa0, pa1, pa2, pa3, pb0, pb1, pb2, pb3, false)
    // phases 1..14: PV(t-1) || S(t), alternating parities (pairs keep names static)
    for (int t = 1; t < NT2 - 1; t += 2) {
        PHASE(t,     pb0, pb1, pb2, pb3, pa0, pa1, pa2, pa3, true)
        PHASE(t + 1, pa0, pa1, pa2, pa3, pb0, pb1, pb2, pb3, true)
    }
    // phase 15: S(15)->pb || PV(14) from pa
    PHASE(NT2 - 1, pb0, pb1, pb2, pb3, pa0, pa1, pa2, pa3, true)
    // final: PV(15) from pb; V slot 15%3 = 0 (resident since phase-15 vmcnt(0))
    {
        const _Float16* vp_ = Vb + ((NT2 - 1) % 3) * 4096;
        DO_PV(vp_, pb0, pb1, pb2, pb3)
    }
    float lsum = ls0 + ls1;

    // ---- combine epilogue: sum the two key-half partials through LDS ----
    __syncthreads();                           // all waves done reading K/V LDS
    float* cb = (float*)smem;                  // [qg][dh][r][lane] = 8192 floats (32 KB)
    float* ls = cb + 4 * 2 * 16 * 64;          // [qg][lane] = 256 floats
    if (kh == 1) {
        #pragma unroll
        for (int r = 0; r < 16; ++r) {
            cb[((qg * 2 + 0) * 16 + r) * 64 + lane] = o0[r];
            cb[((qg * 2 + 1) * 16 + r) * 64 + lane] = o1[r];
        }
        ls[qg * 64 + lane] = lsum;
    }
    __syncthreads();
    if (kh == 0) {
        #pragma unroll
        for (int r = 0; r < 16; ++r) {
            o0[r] += cb[((qg * 2 + 0) * 16 + r) * 64 + lane];
            o1[r] += cb[((qg * 2 + 1) * 16 + r) * 64 + lane];
        }
        lsum += ls[qg * 64 + lane];
        // finalize: per-lane row sums (q = ln, split by hi); combine halves, store
        float v = lsum;
        v += __shfl_xor(v, 32, 64);
        const float inv = 1.0f / v;
        #pragma unroll
        for (int r = 0; r < 16; ++r) {
            const int rl = (r & 3) + 8 * (r >> 2) + 4 * hi;
            const float linv = __shfl(inv, rl, 64);
            const size_t ro = bh_q + (size_t)(q_base + rl) * HD;
            Out[ro + ln]      = o0[r] * linv;
            Out[ro + 32 + ln] = o1[r] * linv;
        }
    }
}

// ---------------- fallback (round-1 verified kernel) if ws too small ----------------
__global__ __launch_bounds__(256, 2)
void fattn_fb_kernel(const float* __restrict__ Q, const float* __restrict__ K,
                     const float* __restrict__ V, float* __restrict__ Out)
{
    __shared__ __align__(16) _Float16 Ks[KT][PLS];
    __shared__ __align__(16) _Float16 Vts[D][PLS];
    __shared__ __align__(16) _Float16 Pwf[4][16][PLS];
    const int tid = threadIdx.x, wave = tid >> 6, lane = tid & 63;
    const int m = lane & 15, quad = lane >> 4;
    const int q_base = blockIdx.x * 64;
    const size_t bh_off = ((size_t)blockIdx.z * N * H + (size_t)blockIdx.y) * D;
    const float SCALE = 0.125f;
    const int qrow = q_base + wave * 16 + m;
    const float* qp = Q + bh_off + (size_t)qrow * HD + quad * 8;
    half8 qf0, qf1;
    #pragma unroll
    for (int j = 0; j < 8; ++j) qf0[j] = (_Float16)(qp[j] * SCALE);
    #pragma unroll
    for (int j = 0; j < 8; ++j) qf1[j] = (_Float16)(qp[32 + j] * SCALE);
    float4_ o[4] = {};
    float mi[4], li[4];
    #pragma unroll
    for (int r = 0; r < 4; ++r) { mi[r] = -1e30f; li[r] = 0.0f; }
    for (int kt = 0; kt < N; kt += KT) {
        __syncthreads();
        {
            const int key = tid >> 2, c0 = (tid & 3) * 16;
            const float* kp = K + bh_off + (size_t)(kt + key) * HD + c0;
            half8 lo, hi;
            #pragma unroll
            for (int j = 0; j < 8; ++j) lo[j] = (_Float16)kp[j];
            #pragma unroll
            for (int j = 0; j < 8; ++j) hi[j] = (_Float16)kp[8 + j];
            *(half8*)&Ks[key][c0] = lo;
            *(half8*)&Ks[key][c0 + 8] = hi;
        }
        {
            const int c0 = (tid & 15) * 4, k0 = (tid >> 4) * 4;
            const float* vp = V + bh_off + (size_t)(kt + k0) * HD + c0;
            #pragma unroll
            for (int c = 0; c < 4; ++c)
                #pragma unroll
                for (int i = 0; i < 4; ++i)
                    Vts[c0 + c][k0 + i] = (_Float16)vp[i * HD + c];
        }
        __syncthreads();
        float4_ s[4];
        #pragma unroll
        for (int blk = 0; blk < 4; ++blk) {
            const int key = blk * 16 + m;
            half8 kf0 = *(const half8*)&Ks[key][quad * 8];
            half8 kf1 = *(const half8*)&Ks[key][32 + quad * 8];
            float4_ acc = {};
            acc = __builtin_amdgcn_mfma_f32_16x16x32_f16(qf0, kf0, acc, 0, 0, 0);
            acc = __builtin_amdgcn_mfma_f32_16x16x32_f16(qf1, kf1, acc, 0, 0, 0);
            s[blk] = acc;
        }
        float alpha[4];
        #pragma unroll
        for (int r = 0; r < 4; ++r) {
            float v0 = fmaxf(fmaxf(s[0][r], s[1][r]), fmaxf(s[2][r], s[3][r]));
            #pragma unroll
            for (int mask = 1; mask < 16; mask <<= 1) v0 = fmaxf(v0, __shfl_xor(v0, mask, 64));
            float mn = fmaxf(mi[r], v0);
            alpha[r] = __expf(mi[r] - mn);
            mi[r] = mn;
        }
        #pragma unroll
        for (int blk = 0; blk < 4; ++blk)
            #pragma unroll
            for (int r = 0; r < 4; ++r) s[blk][r] = __expf(s[blk][r] - mi[r]);
        #pragma unroll
        for (int r = 0; r < 4; ++r) {
            float tt = s[0][r] + s[1][r] + s[2][r] + s[3][r];
            #pragma unroll
            for (int mask = 1; mask < 16; mask <<= 1) tt += __shfl_xor(tt, mask, 64);
            li[r] = li[r] * alpha[r] + tt;
        }
        #pragma unroll
        for (int d = 0; d < 4; ++d)
            #pragma unroll
            for (int r = 0; r < 4; ++r) o[d][r] *= alpha[r];
        #pragma unroll
        for (int blk = 0; blk < 4; ++blk)
            #pragma unroll
            for (int r = 0; r < 4; ++r)
                Pwf[wave][quad * 4 + r][blk * 16 + m] = (_Float16)s[blk][r];
        #pragma unroll
        for (int ks = 0; ks < 2; ++ks) {
            half8 af = *(const half8*)&Pwf[wave][m][ks * 32 + quad * 8];
            #pragma unroll
            for (int d = 0; d < 4; ++d) {
                half8 bf = *(const half8*)&Vts[d * 16 + m][ks * 32 + quad * 8];
                o[d] = __builtin_amdgcn_mfma_f32_16x16x32_f16(af, bf, o[d], 0, 0, 0);
            }
        }
    }
    #pragma unroll
    for (int d = 0; d < 4; ++d)
        #pragma unroll
        for (int r = 0; r < 4; ++r) {
            const int row = q_base + wave * 16 + quad * 4 + r;
            Out[bh_off + (size_t)row * HD + d * 16 + m] = o[d][r] / li[r];
        }
}

extern "C" void kernel_launch(void* const* d_in, const int* in_sizes, int n_in,
                              void* d_out, int out_size, void* d_ws, size_t ws_size,
                              hipStream_t stream) {
    const float* q = (const float*)d_in[0];
    const float* k = (const float*)d_in[1];
    const float* v = (const float*)d_in[2];
    float* out = (float*)d_out;

    const size_t nelem = (size_t)B * N * H * D;           // 4194304
    const size_t need = 2 * nelem * sizeof(_Float16);     // Kf + Vt

    if (ws_size >= need) {
        _Float16* Kf = (_Float16*)d_ws;
        _Float16* Vtr = Kf + nelem;
        prep_kernel<<<dim3(2048 + 1024), 256, 0, stream>>>(k, v, Kf, Vtr);
        fattn12_kernel<<<dim3(N / QT, H, B), 512, 0, stream>>>(q, Kf, Vtr, out);
    } else {
        fattn_fb_kernel<<<dim3(N / 64, H, B), 256, 0, stream>>>(q, k, v, out);
    }
}

// Round 9
// 140.622 us; speedup vs baseline: 1.9696x; 1.7813x over previous
//
#include <hip/hip_runtime.h>

// Problem: attention, q,k,v [B=4, N=2048, H=8, D=64] fp32 -> out same.
#define B 4
#define N 2048
#define H 8
#define D 64
#define HD 512              // row stride (elements) for fixed (b,h)
#define QT 128              // q rows per block (4 q-groups x 32, x 2 key-halves)
#define KT 64               // keys per tile
#define NT2 16              // tiles per key-half (split-K)
#define PLS 72              // prep-kernel LDS pad stride

typedef _Float16 half8 __attribute__((ext_vector_type(8)));
typedef float float4_ __attribute__((ext_vector_type(4)));
typedef float float16_ __attribute__((ext_vector_type(16)));

#define MFMA32(a, b, c) __builtin_amdgcn_mfma_f32_32x32x16_f16((a), (b), (c), 0, 0, 0)

// ---------------- fused prepass: K f32->f16 same layout; V -> Vt [b,h,d,n'] f16 ----------------
// Vt key axis is tau-permuted: position p holds original key tau(p), tau = swap bits 2<->3.
// tau makes the 32x32 MFMA S-tile D-rows line up with the PV A-operand k-slots per lane,
// so P never needs a cross-lane exchange (verified in R2).
__global__ void prep_kernel(const float* __restrict__ K, const float* __restrict__ V,
                            _Float16* __restrict__ Kf, _Float16* __restrict__ Vtr) {
    __shared__ _Float16 tile[64][PLS];
    const int t = threadIdx.x;
    if (blockIdx.x < 2048) {
        const size_t i = (size_t)blockIdx.x * 256 + t;
        const float4_* p = (const float4_*)(K + i * 8);
        float4_ a = p[0], b = p[1];
        half8 hh;
        #pragma unroll
        for (int j = 0; j < 4; ++j) { hh[j] = (_Float16)a[j]; hh[4 + j] = (_Float16)b[j]; }
        *(half8*)(Kf + i * 8) = hh;
    } else {
        const int bid = blockIdx.x - 2048;
        const int nt = bid & 31, h = (bid >> 5) & 7, b = bid >> 8;
        {
            const int i = t >> 2, c0 = (t & 3) * 16;
            const float* vp = V + (size_t)b * N * HD + (size_t)(nt * 64 + i) * HD + h * D + c0;
            #pragma unroll
            for (int j = 0; j < 4; ++j) {
                float4_ a = *(const float4_*)(vp + j * 4);
                #pragma unroll
                for (int c = 0; c < 4; ++c) tile[i][c0 + j * 4 + c] = (_Float16)a[c];
            }
        }
        __syncthreads();
        {
            const int d = t >> 2, n0 = (t & 3) * 16;
            // tau within the 16-run: positions n0+0..7 hold keys n0+{0,1,2,3,8,9,10,11};
            //                        positions n0+8..15 hold keys n0+{4,5,6,7,12,13,14,15}.
            half8 w0, w1;
            #pragma unroll
            for (int j = 0; j < 4; ++j) {
                w0[j]     = tile[n0 + j][d];
                w0[4 + j] = tile[n0 + 8 + j][d];
                w1[j]     = tile[n0 + 4 + j][d];
                w1[4 + j] = tile[n0 + 12 + j][d];
            }
            _Float16* op = Vtr + ((size_t)(b * H + h) * D + d) * N + nt * 64 + n0;
            *(half8*)op = w0;
            *(half8*)(op + 8) = w1;
        }
    }
}

// ------- async staging (chunk-swizzled, group-split); wg in [0,4) covers 16 rows each -------
__device__ __forceinline__ void stage_k(const _Float16* __restrict__ Kbh, int keybase,
                                        _Float16* kb, int wg, int lane) {
    const int rsub = lane >> 3, slot = lane & 7;
    #pragma unroll
    for (int i = 0; i < 2; ++i) {
        const int row = wg * 16 + i * 8 + rsub;
        const int c = slot ^ (row & 7);
        __builtin_amdgcn_global_load_lds(
            (const __attribute__((address_space(1))) void*)(Kbh + (size_t)(keybase + row) * HD + c * 8),
            (__attribute__((address_space(3))) void*)(kb + (wg * 16 + i * 8) * 64), 16, 0, 0);
    }
}
__device__ __forceinline__ void stage_v(const _Float16* __restrict__ Vbh, int keybase,
                                        _Float16* vb, int wg, int lane) {
    const int rsub = lane >> 3, slot = lane & 7;
    #pragma unroll
    for (int i = 0; i < 2; ++i) {
        const int row = wg * 16 + i * 8 + rsub;      // d row
        const int c = slot ^ (row & 7);
        __builtin_amdgcn_global_load_lds(
            (const __attribute__((address_space(1))) void*)(Vbh + (size_t)row * N + keybase + c * 8),
            (__attribute__((address_space(3))) void*)(vb + (wg * 16 + i * 8) * 64), 16, 0, 0);
    }
}

// ---- per-phase compute pieces. P fragments are NAMED scalars threaded through macros.
// ---- (R7 lesson, rule 20.) The R8 spill was NOT naming — it was the 64-VGPR cap from
// ---- __launch_bounds__(512,4): hipcc's 2nd arg is min BLOCKS/CU (CUDA semantics), so
// ---- 4 blocks x 8 waves = 8 waves/SIMD = 64-reg ceiling. (512,2) lifts it to 128. ----
#define DO_S_HALF(KC, KB, PA, PB)                                              \
    {                                                                          \
        float16_ s = {};                                                       \
        __builtin_amdgcn_s_setprio(1);                                         \
        _Pragma("unroll")                                                      \
        for (int ks = 0; ks < 4; ++ks) {                                       \
            const int csw = ((2 * ks + hi) ^ (ln & 7)) * 8;                    \
            half8 a = *(const half8*)((KC) + ((KB) * 32 + ln) * 64 + csw);     \
            s = MFMA32(a, qf[ks], s);                                          \
        }                                                                      \
        __builtin_amdgcn_s_setprio(0);                                         \
        half8 f0, f1;                                                          \
        _Pragma("unroll")                                                      \
        for (int j = 0; j < 8; ++j) {                                          \
            float pa_ = __builtin_amdgcn_exp2f(s[j]);                          \
            float pb_ = __builtin_amdgcn_exp2f(s[8 + j]);                      \
            ls0 += pa_; ls1 += pb_;                                            \
            f0[j] = (_Float16)pa_;                                             \
            f1[j] = (_Float16)pb_;                                             \
        }                                                                      \
        PA = f0; PB = f1;                                                      \
    }

#define PV_STEP(VC, KS, P)                                                     \
    {                                                                          \
        const int csw = ((2 * (KS) + hi) ^ (ln & 7)) * 8;                      \
        half8 b0 = *(const half8*)((VC) + ln * 64 + csw);                      \
        half8 b1 = *(const half8*)((VC) + (32 + ln) * 64 + csw);               \
        o0 = MFMA32(P, b0, o0);                                                \
        o1 = MFMA32(P, b1, o1);                                                \
    }

#define DO_PV(VC, P0, P1, P2, P3)                                              \
    __builtin_amdgcn_s_setprio(1);                                             \
    PV_STEP(VC, 0, P0) PV_STEP(VC, 1, P1)                                      \
    PV_STEP(VC, 2, P2) PV_STEP(VC, 3, P3)                                      \
    __builtin_amdgcn_s_setprio(0);

// Phase T: wait tile T (counted), barrier, S(T)->C0..C3, PV(T-1) from Pp0..Pp3
// (V slot (T-1)%3 == (T+2)%3), barrier, stage tile T+2 (K slot T&1, V slot (T+2)%3).
#define PHASE(T, C0, C1, C2, C3, Pp0, Pp1, Pp2, Pp3, WITHPV)                   \
    {                                                                          \
        if ((T) < NT2 - 1) asm volatile("s_waitcnt vmcnt(4)" ::: "memory");    \
        else               asm volatile("s_waitcnt vmcnt(0)" ::: "memory");    \
        __builtin_amdgcn_s_barrier();                                          \
        __builtin_amdgcn_sched_barrier(0);                                     \
        const _Float16* kc_ = Kb + ((T) & 1) * 4096;                           \
        DO_S_HALF(kc_, 0, C0, C1)                                              \
        DO_S_HALF(kc_, 1, C2, C3)                                              \
        if (WITHPV) {                                                          \
            const _Float16* vp_ = Vb + (((T) + 2) % 3) * 4096;                 \
            DO_PV(vp_, Pp0, Pp1, Pp2, Pp3)                                     \
        }                                                                      \
        if ((T) + 2 < NT2) {                                                   \
            __builtin_amdgcn_s_barrier();                                      \
            __builtin_amdgcn_sched_barrier(0);                                 \
            stage_k(Kbh, tbase + ((T) + 2) * KT, Kb + ((T) & 1) * 4096, qg, lane); \
            stage_v(Vbh, tbase + ((T) + 2) * KT, Vb + (((T) + 2) % 3) * 4096, qg, lane); \
        }                                                                      \
    }

// ---- main: split-K, 8 waves (4 qg x 2 kh), PV(t-1)||S(t) via named pf-dbuf, K dbuf + V tbuf ----
__global__ __launch_bounds__(512, 2)
void fattn13_kernel(const float* __restrict__ Q, const _Float16* __restrict__ Kf,
                    const _Float16* __restrict__ Vt, float* __restrict__ Out)
{
    // 80 KB: per stream K dbuf 2x4096 + V tbuf 3x4096 (halves). Epilogue reuses as f32 scratch.
    static __shared__ __align__(16) _Float16 smem[40960];

    const int tid  = threadIdx.x;
    const int wave = tid >> 6;
    const int lane = tid & 63;
    const int ln   = lane & 31;
    const int hi   = lane >> 5;
    const int qg   = wave & 3;      // q-group: 32 q-rows
    const int kh   = wave >> 2;     // key-half: tiles [kh*16, kh*16+16)

    const int h = blockIdx.y;
    const int b = blockIdx.z;
    const int q_base = blockIdx.x * QT + qg * 32;

    const size_t bh_q = (size_t)b * N * HD + (size_t)h * D;
    const _Float16* Kbh = Kf + bh_q;
    const _Float16* Vbh = Vt + (size_t)(b * H + h) * D * N;

    _Float16* Kb = smem + kh * 8192;             // [2][4096]
    _Float16* Vb = smem + 16384 + kh * 12288;    // [3][4096]

    // Q rows in registers as S^T B-frags: qf[ks][j] = Q[q_base+ln][ks*16+hi*8+j]*SC
    const float SC = 0.125f * 1.4426950408889634f;
    half8 qf[4];
    {
        const float* qp = Q + bh_q + (size_t)(q_base + ln) * HD + hi * 8;
        #pragma unroll
        for (int ks = 0; ks < 4; ++ks) {
            float4_ a0 = *(const float4_*)(qp + ks * 16);
            float4_ a1 = *(const float4_*)(qp + ks * 16 + 4);
            half8 f;
            #pragma unroll
            for (int j = 0; j < 4; ++j) { f[j] = (_Float16)(a0[j] * SC); f[4 + j] = (_Float16)(a1[j] * SC); }
            qf[ks] = f;
        }
    }

    float16_ o0 = {}, o1 = {};
    float ls0 = 0.f, ls1 = 0.f;
    half8 pa0, pa1, pa2, pa3;       // P fragments, phase parity A
    half8 pb0, pb1, pb2, pb3;       // P fragments, phase parity B

    const int tbase = kh * NT2 * KT;

    // prologue: stage tiles 0 and 1 (K slots 0,1; V slots 0,1); 8 vmem ops per wave
    stage_k(Kbh, tbase, Kb, qg, lane);              stage_v(Vbh, tbase, Vb, qg, lane);
    stage_k(Kbh, tbase + KT, Kb + 4096, qg, lane);  stage_v(Vbh, tbase + KT, Vb + 4096, qg, lane);

    // phase 0: S(0)->pa only
    PHASE(0, pa0, pa1, pa2, pa3, pb0, pb1, pb2, pb3, false)
    // phases 1..14: PV(t-1) || S(t), alternating parities (pairs keep names static)
    for (int t = 1; t < NT2 - 1; t += 2) {
        PHASE(t,     pb0, pb1, pb2, pb3, pa0, pa1, pa2, pa3, true)
        PHASE(t + 1, pa0, pa1, pa2, pa3, pb0, pb1, pb2, pb3, true)
    }
    // phase 15: S(15)->pb || PV(14) from pa
    PHASE(NT2 - 1, pb0, pb1, pb2, pb3, pa0, pa1, pa2, pa3, true)
    // final: PV(15) from pb; V slot 15%3 = 0 (resident since phase-15 vmcnt(0))
    {
        const _Float16* vp_ = Vb + ((NT2 - 1) % 3) * 4096;
        DO_PV(vp_, pb0, pb1, pb2, pb3)
    }
    float lsum = ls0 + ls1;

    // ---- combine epilogue: sum the two key-half partials through LDS ----
    __syncthreads();                           // all waves done reading K/V LDS
    float* cb = (float*)smem;                  // [qg][dh][r][lane] = 8192 floats (32 KB)
    float* ls = cb + 4 * 2 * 16 * 64;          // [qg][lane] = 256 floats
    if (kh == 1) {
        #pragma unroll
        for (int r = 0; r < 16; ++r) {
            cb[((qg * 2 + 0) * 16 + r) * 64 + lane] = o0[r];
            cb[((qg * 2 + 1) * 16 + r) * 64 + lane] = o1[r];
        }
        ls[qg * 64 + lane] = lsum;
    }
    __syncthreads();
    if (kh == 0) {
        #pragma unroll
        for (int r = 0; r < 16; ++r) {
            o0[r] += cb[((qg * 2 + 0) * 16 + r) * 64 + lane];
            o1[r] += cb[((qg * 2 + 1) * 16 + r) * 64 + lane];
        }
        lsum += ls[qg * 64 + lane];
        // finalize: per-lane row sums (q = ln, split by hi); combine halves, store
        float v = lsum;
        v += __shfl_xor(v, 32, 64);
        const float inv = 1.0f / v;
        #pragma unroll
        for (int r = 0; r < 16; ++r) {
            const int rl = (r & 3) + 8 * (r >> 2) + 4 * hi;
            const float linv = __shfl(inv, rl, 64);
            const size_t ro = bh_q + (size_t)(q_base + rl) * HD;
            Out[ro + ln]      = o0[r] * linv;
            Out[ro + 32 + ln] = o1[r] * linv;
        }
    }
}

// ---------------- fallback (round-1 verified kernel) if ws too small ----------------
__global__ __launch_bounds__(256, 2)
void fattn_fb_kernel(const float* __restrict__ Q, const float* __restrict__ K,
                     const float* __restrict__ V, float* __restrict__ Out)
{
    __shared__ __align__(16) _Float16 Ks[KT][PLS];
    __shared__ __align__(16) _Float16 Vts[D][PLS];
    __shared__ __align__(16) _Float16 Pwf[4][16][PLS];
    const int tid = threadIdx.x, wave = tid >> 6, lane = tid & 63;
    const int m = lane & 15, quad = lane >> 4;
    const int q_base = blockIdx.x * 64;
    const size_t bh_off = ((size_t)blockIdx.z * N * H + (size_t)blockIdx.y) * D;
    const float SCALE = 0.125f;
    const int qrow = q_base + wave * 16 + m;
    const float* qp = Q + bh_off + (size_t)qrow * HD + quad * 8;
    half8 qf0, qf1;
    #pragma unroll
    for (int j = 0; j < 8; ++j) qf0[j] = (_Float16)(qp[j] * SCALE);
    #pragma unroll
    for (int j = 0; j < 8; ++j) qf1[j] = (_Float16)(qp[32 + j] * SCALE);
    float4_ o[4] = {};
    float mi[4], li[4];
    #pragma unroll
    for (int r = 0; r < 4; ++r) { mi[r] = -1e30f; li[r] = 0.0f; }
    for (int kt = 0; kt < N; kt += KT) {
        __syncthreads();
        {
            const int key = tid >> 2, c0 = (tid & 3) * 16;
            const float* kp = K + bh_off + (size_t)(kt + key) * HD + c0;
            half8 lo, hi;
            #pragma unroll
            for (int j = 0; j < 8; ++j) lo[j] = (_Float16)kp[j];
            #pragma unroll
            for (int j = 0; j < 8; ++j) hi[j] = (_Float16)kp[8 + j];
            *(half8*)&Ks[key][c0] = lo;
            *(half8*)&Ks[key][c0 + 8] = hi;
        }
        {
            const int c0 = (tid & 15) * 4, k0 = (tid >> 4) * 4;
            const float* vp = V + bh_off + (size_t)(kt + k0) * HD + c0;
            #pragma unroll
            for (int c = 0; c < 4; ++c)
                #pragma unroll
                for (int i = 0; i < 4; ++i)
                    Vts[c0 + c][k0 + i] = (_Float16)vp[i * HD + c];
        }
        __syncthreads();
        float4_ s[4];
        #pragma unroll
        for (int blk = 0; blk < 4; ++blk) {
            const int key = blk * 16 + m;
            half8 kf0 = *(const half8*)&Ks[key][quad * 8];
            half8 kf1 = *(const half8*)&Ks[key][32 + quad * 8];
            float4_ acc = {};
            acc = __builtin_amdgcn_mfma_f32_16x16x32_f16(qf0, kf0, acc, 0, 0, 0);
            acc = __builtin_amdgcn_mfma_f32_16x16x32_f16(qf1, kf1, acc, 0, 0, 0);
            s[blk] = acc;
        }
        float alpha[4];
        #pragma unroll
        for (int r = 0; r < 4; ++r) {
            float v0 = fmaxf(fmaxf(s[0][r], s[1][r]), fmaxf(s[2][r], s[3][r]));
            #pragma unroll
            for (int mask = 1; mask < 16; mask <<= 1) v0 = fmaxf(v0, __shfl_xor(v0, mask, 64));
            float mn = fmaxf(mi[r], v0);
            alpha[r] = __expf(mi[r] - mn);
            mi[r] = mn;
        }
        #pragma unroll
        for (int blk = 0; blk < 4; ++blk)
            #pragma unroll
            for (int r = 0; r < 4; ++r) s[blk][r] = __expf(s[blk][r] - mi[r]);
        #pragma unroll
        for (int r = 0; r < 4; ++r) {
            float tt = s[0][r] + s[1][r] + s[2][r] + s[3][r];
            #pragma unroll
            for (int mask = 1; mask < 16; mask <<= 1) tt += __shfl_xor(tt, mask, 64);
            li[r] = li[r] * alpha[r] + tt;
        }
        #pragma unroll
        for (int d = 0; d < 4; ++d)
            #pragma unroll
            for (int r = 0; r < 4; ++r) o[d][r] *= alpha[r];
        #pragma unroll
        for (int blk = 0; blk < 4; ++blk)
            #pragma unroll
            for (int r = 0; r < 4; ++r)
                Pwf[wave][quad * 4 + r][blk * 16 + m] = (_Float16)s[blk][r];
        #pragma unroll
        for (int ks = 0; ks < 2; ++ks) {
            half8 af = *(const half8*)&Pwf[wave][m][ks * 32 + quad * 8];
            #pragma unroll
            for (int d = 0; d < 4; ++d) {
                half8 bf = *(const half8*)&Vts[d * 16 + m][ks * 32 + quad * 8];
                o[d] = __builtin_amdgcn_mfma_f32_16x16x32_f16(af, bf, o[d], 0, 0, 0);
            }
        }
    }
    #pragma unroll
    for (int d = 0; d < 4; ++d)
        #pragma unroll
        for (int r = 0; r < 4; ++r) {
            const int row = q_base + wave * 16 + quad * 4 + r;
            Out[bh_off + (size_t)row * HD + d * 16 + m] = o[d][r] / li[r];
        }
}

extern "C" void kernel_launch(void* const* d_in, const int* in_sizes, int n_in,
                              void* d_out, int out_size, void* d_ws, size_t ws_size,
                              hipStream_t stream) {
    const float* q = (const float*)d_in[0];
    const float* k = (const float*)d_in[1];
    const float* v = (const float*)d_in[2];
    float* out = (float*)d_out;

    const size_t nelem = (size_t)B * N * H * D;           // 4194304
    const size_t need = 2 * nelem * sizeof(_Float16);     // Kf + Vt

    if (ws_size >= need) {
        _Float16* Kf = (_Float16*)d_ws;
        _Float16* Vtr = Kf + nelem;
        prep_kernel<<<dim3(2048 + 1024), 256, 0, stream>>>(k, v, Kf, Vtr);
        fattn13_kernel<<<dim3(N / QT, H, B), 512, 0, stream>>>(q, Kf, Vtr, out);
    } else {
        fattn_fb_kernel<<<dim3(N / 64, H, B), 256, 0, stream>>>(q, k, v, out);
    }
}

// Round 10
// 139.699 us; speedup vs baseline: 1.9826x; 1.0066x over previous
//
#include <hip/hip_runtime.h>

// Problem: attention, q,k,v [B=4, N=2048, H=8, D=64] fp32 -> out same.
#define B 4
#define N 2048
#define H 8
#define D 64
#define HD 512              // row stride (elements) for fixed (b,h)
#define QT 128              // q rows per block (4 q-groups x 32, x 2 key-halves)
#define KT 64               // keys per tile
#define NT2 16              // tiles per key-half (split-K)
#define PLS 72              // prep-kernel LDS pad stride

typedef _Float16 half8 __attribute__((ext_vector_type(8)));
typedef float float4_ __attribute__((ext_vector_type(4)));
typedef float float16_ __attribute__((ext_vector_type(16)));

#define MFMA32(a, b, c) __builtin_amdgcn_mfma_f32_32x32x16_f16((a), (b), (c), 0, 0, 0)

// ---------------- fused prepass: K f32->f16 same layout; V -> Vt [b,h,d,n'] f16 ----------------
// Vt key axis is tau-permuted: position p holds original key tau(p), tau = swap bits 2<->3.
// tau makes the 32x32 MFMA S-tile D-rows line up with the PV A-operand k-slots per lane,
// so P never needs a cross-lane exchange (verified in R2).
__global__ void prep_kernel(const float* __restrict__ K, const float* __restrict__ V,
                            _Float16* __restrict__ Kf, _Float16* __restrict__ Vtr) {
    __shared__ _Float16 tile[64][PLS];
    const int t = threadIdx.x;
    if (blockIdx.x < 2048) {
        const size_t i = (size_t)blockIdx.x * 256 + t;
        const float4_* p = (const float4_*)(K + i * 8);
        float4_ a = p[0], b = p[1];
        half8 hh;
        #pragma unroll
        for (int j = 0; j < 4; ++j) { hh[j] = (_Float16)a[j]; hh[4 + j] = (_Float16)b[j]; }
        *(half8*)(Kf + i * 8) = hh;
    } else {
        const int bid = blockIdx.x - 2048;
        const int nt = bid & 31, h = (bid >> 5) & 7, b = bid >> 8;
        {
            const int i = t >> 2, c0 = (t & 3) * 16;
            const float* vp = V + (size_t)b * N * HD + (size_t)(nt * 64 + i) * HD + h * D + c0;
            #pragma unroll
            for (int j = 0; j < 4; ++j) {
                float4_ a = *(const float4_*)(vp + j * 4);
                #pragma unroll
                for (int c = 0; c < 4; ++c) tile[i][c0 + j * 4 + c] = (_Float16)a[c];
            }
        }
        __syncthreads();
        {
            const int d = t >> 2, n0 = (t & 3) * 16;
            // tau within the 16-run: positions n0+0..7 hold keys n0+{0,1,2,3,8,9,10,11};
            //                        positions n0+8..15 hold keys n0+{4,5,6,7,12,13,14,15}.
            half8 w0, w1;
            #pragma unroll
            for (int j = 0; j < 4; ++j) {
                w0[j]     = tile[n0 + j][d];
                w0[4 + j] = tile[n0 + 8 + j][d];
                w1[j]     = tile[n0 + 4 + j][d];
                w1[4 + j] = tile[n0 + 12 + j][d];
            }
            _Float16* op = Vtr + ((size_t)(b * H + h) * D + d) * N + nt * 64 + n0;
            *(half8*)op = w0;
            *(half8*)(op + 8) = w1;
        }
    }
}

// ------- async staging (chunk-swizzled, group-split); wg in [0,4) covers 16 rows each -------
__device__ __forceinline__ void stage_k(const _Float16* __restrict__ Kbh, int keybase,
                                        _Float16* kb, int wg, int lane) {
    const int rsub = lane >> 3, slot = lane & 7;
    #pragma unroll
    for (int i = 0; i < 2; ++i) {
        const int row = wg * 16 + i * 8 + rsub;
        const int c = slot ^ (row & 7);
        __builtin_amdgcn_global_load_lds(
            (const __attribute__((address_space(1))) void*)(Kbh + (size_t)(keybase + row) * HD + c * 8),
            (__attribute__((address_space(3))) void*)(kb + (wg * 16 + i * 8) * 64), 16, 0, 0);
    }
}
__device__ __forceinline__ void stage_v(const _Float16* __restrict__ Vbh, int keybase,
                                        _Float16* vb, int wg, int lane) {
    const int rsub = lane >> 3, slot = lane & 7;
    #pragma unroll
    for (int i = 0; i < 2; ++i) {
        const int row = wg * 16 + i * 8 + rsub;      // d row
        const int c = slot ^ (row & 7);
        __builtin_amdgcn_global_load_lds(
            (const __attribute__((address_space(1))) void*)(Vbh + (size_t)row * N + keybase + c * 8),
            (__attribute__((address_space(3))) void*)(vb + (wg * 16 + i * 8) * 64), 16, 0, 0);
    }
}

// ---- per-phase compute pieces. P fragments are NAMED scalars threaded through macros
// ---- (rule 20; R7/R8 lesson). R9 lesson: V tbuf pushed LDS to 80 KB -> 1 block/CU ->
// ---- 2 waves/SIMD -> 65 us. Fix: ASYMMETRIC staging (K 2-ahead, V 1-ahead) makes V
// ---- dbuf legal again -> 64 KB -> 2 blocks/CU. Ledger: group G_t = {K(t+2), V(t+1)}
// ---- staged at end of phase t; top-of-phase vmcnt(4) retires G_{t-2}. ----
#define DO_S_HALF(KC, KB, PA, PB)                                              \
    {                                                                          \
        float16_ s = {};                                                       \
        __builtin_amdgcn_s_setprio(1);                                         \
        _Pragma("unroll")                                                      \
        for (int ks = 0; ks < 4; ++ks) {                                       \
            const int csw = ((2 * ks + hi) ^ (ln & 7)) * 8;                    \
            half8 a = *(const half8*)((KC) + ((KB) * 32 + ln) * 64 + csw);     \
            s = MFMA32(a, qf[ks], s);                                          \
        }                                                                      \
        __builtin_amdgcn_s_setprio(0);                                         \
        half8 f0, f1;                                                          \
        _Pragma("unroll")                                                      \
        for (int j = 0; j < 8; ++j) {                                          \
            float pa_ = __builtin_amdgcn_exp2f(s[j]);                          \
            float pb_ = __builtin_amdgcn_exp2f(s[8 + j]);                      \
            ls0 += pa_; ls1 += pb_;                                            \
            f0[j] = (_Float16)pa_;                                             \
            f1[j] = (_Float16)pb_;                                             \
        }                                                                      \
        PA = f0; PB = f1;                                                      \
    }

#define PV_STEP(VC, KS, P)                                                     \
    {                                                                          \
        const int csw = ((2 * (KS) + hi) ^ (ln & 7)) * 8;                      \
        half8 b0 = *(const half8*)((VC) + ln * 64 + csw);                      \
        half8 b1 = *(const half8*)((VC) + (32 + ln) * 64 + csw);               \
        o0 = MFMA32(P, b0, o0);                                                \
        o1 = MFMA32(P, b1, o1);                                                \
    }

#define DO_PV(VC, P0, P1, P2, P3)                                              \
    __builtin_amdgcn_s_setprio(1);                                             \
    PV_STEP(VC, 0, P0) PV_STEP(VC, 1, P1)                                      \
    PV_STEP(VC, 2, P2) PV_STEP(VC, 3, P3)                                      \
    __builtin_amdgcn_s_setprio(0);

// Phase T: vmcnt(WAITN) retires G_{T-2} (K(T), V(T-1) landed), barrier,
// S(T)->C0..C3 from K slot T&1, PV(T-1) from Pp* with V slot (T-1)&1,
// end-barrier (all reads of K(T), V(T-1) done), stage K(T+2)->slot T&1,
// V(T+1)->slot (T+1)&1 (= V(T-1)'s slot, just freed).
#define PHASE(T, C0, C1, C2, C3, Pp0, Pp1, Pp2, Pp3, WITHPV, WAITN)            \
    {                                                                          \
        asm volatile("s_waitcnt vmcnt(" #WAITN ")" ::: "memory");              \
        __builtin_amdgcn_s_barrier();                                          \
        __builtin_amdgcn_sched_barrier(0);                                     \
        const _Float16* kc_ = Kb + ((T) & 1) * 4096;                           \
        DO_S_HALF(kc_, 0, C0, C1)                                              \
        DO_S_HALF(kc_, 1, C2, C3)                                              \
        if (WITHPV) {                                                          \
            const _Float16* vp_ = Vb + (((T) - 1) & 1) * 4096;                 \
            DO_PV(vp_, Pp0, Pp1, Pp2, Pp3)                                     \
        }                                                                      \
        if ((T) + 1 < NT2) {                                                   \
            __builtin_amdgcn_s_barrier();                                      \
            __builtin_amdgcn_sched_barrier(0);                                 \
            if ((T) + 2 < NT2)                                                 \
                stage_k(Kbh, tbase + ((T) + 2) * KT, Kb + ((T) & 1) * 4096, qg, lane); \
            stage_v(Vbh, tbase + ((T) + 1) * KT, Vb + (((T) + 1) & 1) * 4096, qg, lane); \
        }                                                                      \
    }

// ---- main: split-K, 8 waves (4 qg x 2 kh), PV(t-1)||S(t), K dbuf + V dbuf, 64 KB ----
__global__ __launch_bounds__(512, 2)
void fattn14_kernel(const float* __restrict__ Q, const _Float16* __restrict__ Kf,
                    const _Float16* __restrict__ Vt, float* __restrict__ Out)
{
    // 64 KB: per stream K dbuf 2x4096 + V dbuf 2x4096 (halves). Epilogue reuses as f32 scratch.
    static __shared__ __align__(16) _Float16 smem[32768];

    const int tid  = threadIdx.x;
    const int wave = tid >> 6;
    const int lane = tid & 63;
    const int ln   = lane & 31;
    const int hi   = lane >> 5;
    const int qg   = wave & 3;      // q-group: 32 q-rows
    const int kh   = wave >> 2;     // key-half: tiles [kh*16, kh*16+16)

    const int h = blockIdx.y;
    const int b = blockIdx.z;
    const int q_base = blockIdx.x * QT + qg * 32;

    const size_t bh_q = (size_t)b * N * HD + (size_t)h * D;
    const _Float16* Kbh = Kf + bh_q;
    const _Float16* Vbh = Vt + (size_t)(b * H + h) * D * N;

    _Float16* Kb = smem + kh * 8192;             // [2][4096]
    _Float16* Vb = smem + 16384 + kh * 8192;     // [2][4096]

    // Q rows in registers as S^T B-frags: qf[ks][j] = Q[q_base+ln][ks*16+hi*8+j]*SC
    const float SC = 0.125f * 1.4426950408889634f;
    half8 qf[4];
    {
        const float* qp = Q + bh_q + (size_t)(q_base + ln) * HD + hi * 8;
        #pragma unroll
        for (int ks = 0; ks < 4; ++ks) {
            float4_ a0 = *(const float4_*)(qp + ks * 16);
            float4_ a1 = *(const float4_*)(qp + ks * 16 + 4);
            half8 f;
            #pragma unroll
            for (int j = 0; j < 4; ++j) { f[j] = (_Float16)(a0[j] * SC); f[4 + j] = (_Float16)(a1[j] * SC); }
            qf[ks] = f;
        }
    }

    float16_ o0 = {}, o1 = {};
    float ls0 = 0.f, ls1 = 0.f;
    half8 pa0, pa1, pa2, pa3;       // P fragments, phase parity A
    half8 pb0, pb1, pb2, pb3;       // P fragments, phase parity B

    const int tbase = kh * NT2 * KT;

    // prologue: K(0)->slot0, V(0)->slot0, K(1)->slot1 (6 vmem ops per wave).
    // Phase 0's vmcnt(4) retires exactly K(0).
    stage_k(Kbh, tbase, Kb, qg, lane);
    stage_v(Vbh, tbase, Vb, qg, lane);
    stage_k(Kbh, tbase + KT, Kb + 4096, qg, lane);

    // phase 0: S(0)->pa only; end stages {K(2), V(1)}
    PHASE(0, pa0, pa1, pa2, pa3, pb0, pb1, pb2, pb3, false, 4)
    // phases 1..14: PV(t-1) || S(t), alternating parities
    for (int t = 1; t < NT2 - 1; t += 2) {
        PHASE(t,     pb0, pb1, pb2, pb3, pa0, pa1, pa2, pa3, true, 4)
        PHASE(t + 1, pa0, pa1, pa2, pa3, pb0, pb1, pb2, pb3, true, 4)
    }
    // phase 15: S(15)->pb || PV(14) from pa. Outstanding: G_13{K15,V14}(4)+G_14{V15}(2)
    // -> vmcnt(2) retires G_13. No staging at end (T+1 == NT2).
    PHASE(NT2 - 1, pb0, pb1, pb2, pb3, pa0, pa1, pa2, pa3, true, 2)
    // final: PV(15) from pb; V(15) in slot 1 — drain own loads + barrier for other waves'.
    asm volatile("s_waitcnt vmcnt(0)" ::: "memory");
    __builtin_amdgcn_s_barrier();
    __builtin_amdgcn_sched_barrier(0);
    {
        const _Float16* vp_ = Vb + ((NT2 - 1) & 1) * 4096;
        DO_PV(vp_, pb0, pb1, pb2, pb3)
    }
    float lsum = ls0 + ls1;

    // ---- combine epilogue: sum the two key-half partials through LDS ----
    __syncthreads();                           // all waves done reading K/V LDS
    float* cb = (float*)smem;                  // [qg][dh][r][lane] = 8192 floats (32 KB)
    float* ls = cb + 4 * 2 * 16 * 64;          // [qg][lane] = 256 floats
    if (kh == 1) {
        #pragma unroll
        for (int r = 0; r < 16; ++r) {
            cb[((qg * 2 + 0) * 16 + r) * 64 + lane] = o0[r];
            cb[((qg * 2 + 1) * 16 + r) * 64 + lane] = o1[r];
        }
        ls[qg * 64 + lane] = lsum;
    }
    __syncthreads();
    if (kh == 0) {
        #pragma unroll
        for (int r = 0; r < 16; ++r) {
            o0[r] += cb[((qg * 2 + 0) * 16 + r) * 64 + lane];
            o1[r] += cb[((qg * 2 + 1) * 16 + r) * 64 + lane];
        }
        lsum += ls[qg * 64 + lane];
        // finalize: per-lane row sums (q = ln, split by hi); combine halves, store
        float v = lsum;
        v += __shfl_xor(v, 32, 64);
        const float inv = 1.0f / v;
        #pragma unroll
        for (int r = 0; r < 16; ++r) {
            const int rl = (r & 3) + 8 * (r >> 2) + 4 * hi;
            const float linv = __shfl(inv, rl, 64);
            const size_t ro = bh_q + (size_t)(q_base + rl) * HD;
            Out[ro + ln]      = o0[r] * linv;
            Out[ro + 32 + ln] = o1[r] * linv;
        }
    }
}

// ---------------- fallback (round-1 verified kernel) if ws too small ----------------
__global__ __launch_bounds__(256, 2)
void fattn_fb_kernel(const float* __restrict__ Q, const float* __restrict__ K,
                     const float* __restrict__ V, float* __restrict__ Out)
{
    __shared__ __align__(16) _Float16 Ks[KT][PLS];
    __shared__ __align__(16) _Float16 Vts[D][PLS];
    __shared__ __align__(16) _Float16 Pwf[4][16][PLS];
    const int tid = threadIdx.x, wave = tid >> 6, lane = tid & 63;
    const int m = lane & 15, quad = lane >> 4;
    const int q_base = blockIdx.x * 64;
    const size_t bh_off = ((size_t)blockIdx.z * N * H + (size_t)blockIdx.y) * D;
    const float SCALE = 0.125f;
    const int qrow = q_base + wave * 16 + m;
    const float* qp = Q + bh_off + (size_t)qrow * HD + quad * 8;
    half8 qf0, qf1;
    #pragma unroll
    for (int j = 0; j < 8; ++j) qf0[j] = (_Float16)(qp[j] * SCALE);
    #pragma unroll
    for (int j = 0; j < 8; ++j) qf1[j] = (_Float16)(qp[32 + j] * SCALE);
    float4_ o[4] = {};
    float mi[4], li[4];
    #pragma unroll
    for (int r = 0; r < 4; ++r) { mi[r] = -1e30f; li[r] = 0.0f; }
    for (int kt = 0; kt < N; kt += KT) {
        __syncthreads();
        {
            const int key = tid >> 2, c0 = (tid & 3) * 16;
            const float* kp = K + bh_off + (size_t)(kt + key) * HD + c0;
            half8 lo, hi;
            #pragma unroll
            for (int j = 0; j < 8; ++j) lo[j] = (_Float16)kp[j];
            #pragma unroll
            for (int j = 0; j < 8; ++j) hi[j] = (_Float16)kp[8 + j];
            *(half8*)&Ks[key][c0] = lo;
            *(half8*)&Ks[key][c0 + 8] = hi;
        }
        {
            const int c0 = (tid & 15) * 4, k0 = (tid >> 4) * 4;
            const float* vp = V + bh_off + (size_t)(kt + k0) * HD + c0;
            #pragma unroll
            for (int c = 0; c < 4; ++c)
                #pragma unroll
                for (int i = 0; i < 4; ++i)
                    Vts[c0 + c][k0 + i] = (_Float16)vp[i * HD + c];
        }
        __syncthreads();
        float4_ s[4];
        #pragma unroll
        for (int blk = 0; blk < 4; ++blk) {
            const int key = blk * 16 + m;
            half8 kf0 = *(const half8*)&Ks[key][quad * 8];
            half8 kf1 = *(const half8*)&Ks[key][32 + quad * 8];
            float4_ acc = {};
            acc = __builtin_amdgcn_mfma_f32_16x16x32_f16(qf0, kf0, acc, 0, 0, 0);
            acc = __builtin_amdgcn_mfma_f32_16x16x32_f16(qf1, kf1, acc, 0, 0, 0);
            s[blk] = acc;
        }
        float alpha[4];
        #pragma unroll
        for (int r = 0; r < 4; ++r) {
            float v0 = fmaxf(fmaxf(s[0][r], s[1][r]), fmaxf(s[2][r], s[3][r]));
            #pragma unroll
            for (int mask = 1; mask < 16; mask <<= 1) v0 = fmaxf(v0, __shfl_xor(v0, mask, 64));
            float mn = fmaxf(mi[r], v0);
            alpha[r] = __expf(mi[r] - mn);
            mi[r] = mn;
        }
        #pragma unroll
        for (int blk = 0; blk < 4; ++blk)
            #pragma unroll
            for (int r = 0; r < 4; ++r) s[blk][r] = __expf(s[blk][r] - mi[r]);
        #pragma unroll
        for (int r = 0; r < 4; ++r) {
            float tt = s[0][r] + s[1][r] + s[2][r] + s[3][r];
            #pragma unroll
            for (int mask = 1; mask < 16; mask <<= 1) tt += __shfl_xor(tt, mask, 64);
            li[r] = li[r] * alpha[r] + tt;
        }
        #pragma unroll
        for (int d = 0; d < 4; ++d)
            #pragma unroll
            for (int r = 0; r < 4; ++r) o[d][r] *= alpha[r];
        #pragma unroll
        for (int blk = 0; blk < 4; ++blk)
            #pragma unroll
            for (int r = 0; r < 4; ++r)
                Pwf[wave][quad * 4 + r][blk * 16 + m] = (_Float16)s[blk][r];
        #pragma unroll
        for (int ks = 0; ks < 2; ++ks) {
            half8 af = *(const half8*)&Pwf[wave][m][ks * 32 + quad * 8];
            #pragma unroll
            for (int d = 0; d < 4; ++d) {
                half8 bf = *(const half8*)&Vts[d * 16 + m][ks * 32 + quad * 8];
                o[d] = __builtin_amdgcn_mfma_f32_16x16x32_f16(af, bf, o[d], 0, 0, 0);
            }
        }
    }
    #pragma unroll
    for (int d = 0; d < 4; ++d)
        #pragma unroll
        for (int r = 0; r < 4; ++r) {
            const int row = q_base + wave * 16 + quad * 4 + r;
            Out[bh_off + (size_t)row * HD + d * 16 + m] = o[d][r] / li[r];
        }
}

extern "C" void kernel_launch(void* const* d_in, const int* in_sizes, int n_in,
                              void* d_out, int out_size, void* d_ws, size_t ws_size,
                              hipStream_t stream) {
    const float* q = (const float*)d_in[0];
    const float* k = (const float*)d_in[1];
    const float* v = (const float*)d_in[2];
    float* out = (float*)d_out;

    const size_t nelem = (size_t)B * N * H * D;           // 4194304
    const size_t need = 2 * nelem * sizeof(_Float16);     // Kf + Vt

    if (ws_size >= need) {
        _Float16* Kf = (_Float16*)d_ws;
        _Float16* Vtr = Kf + nelem;
        prep_kernel<<<dim3(2048 + 1024), 256, 0, stream>>>(k, v, Kf, Vtr);
        fattn14_kernel<<<dim3(N / QT, H, B), 512, 0, stream>>>(q, Kf, Vtr, out);
    } else {
        fattn_fb_kernel<<<dim3(N / 64, H, B), 256, 0, stream>>>(q, k, v, out);
    }
}